// Round 11
// baseline (342.953 us; speedup 1.0000x reference)
//
#include <hip/hip_runtime.h>
#include <math.h>

#define EPS 1e-7f

constexpr int SIZE_IN = 14;
constexpr int P_  = 36;   // 6x6 parent positions
constexpr int Cc  = 288;  // children per parent (3*3*32)
constexpr int O_  = 32;   // output capsules
constexpr int G_  = 4;    // child groups per parent (grid-split path)
constexpr int CG  = Cc / G_;   // 72 children per group
constexpr int NTG = CG / 8;    // 9 children per thread in split path
constexpr int THREADS = 256;
constexpr int NBP = 8 * P_;    // 288 (b,p) pairs
constexpr int MIVS = 36;       // MIV stride per o: m[16] @0, iv[16] @16, zb @32 (16B-aligned)

// ---- DPP-based butterfly reductions (validated round 8: -17% vs __shfl_xor) ----
template<int CTRL>
__device__ __forceinline__ float dppf(float x) {
    int xi = __builtin_bit_cast(int, x);
    return __builtin_bit_cast(float,
        __builtin_amdgcn_update_dpp(xi, xi, CTRL, 0xf, 0xf, true));
}
__device__ __forceinline__ float swz16(float x) {
    return __builtin_bit_cast(float,
        __builtin_amdgcn_ds_swizzle(__builtin_bit_cast(int, x), 0x401F));
}
__device__ __forceinline__ float red32_max(float x) {
    x = fmaxf(x, dppf<0xB1>(x));
    x = fmaxf(x, dppf<0x4E>(x));
    x = fmaxf(x, dppf<0x141>(x));
    x = fmaxf(x, dppf<0x140>(x));
    x = fmaxf(x, swz16(x));
    return x;
}
__device__ __forceinline__ float red32_sum(float x) {
    x += dppf<0xB1>(x);
    x += dppf<0x4E>(x);
    x += dppf<0x141>(x);
    x += dppf<0x140>(x);
    x += swz16(x);
    return x;
}
__device__ __forceinline__ float red16_sum(float x) {  // within 16-lane groups
    x += dppf<0xB1>(x);
    x += dppf<0x4E>(x);
    x += dppf<0x141>(x);
    x += dppf<0x140>(x);
    return x;
}

#define F4_TO_ARR(dst, off, f4) \
    dst[(off)+0] = (f4).x; dst[(off)+1] = (f4).y; dst[(off)+2] = (f4).z; dst[(off)+3] = (f4).w;

// ===================== PATH A: grid-split pipeline (lean pass + separate fin) =====================
// P slot layout: P[((bp*G_ + g)*O_ + o)*33 + k], k: 0=S0, 1..16=S1, 17..32=S2
// REGISTER-SHAPE NOTE (measured r8 vs r10): finalize at the TAIL of a kernel (after the child
// loop, S/m/iv dead) fits in 96 VGPR; the SAME finalize at the HEAD (r10) pushed the kernel to
// the 128-VGPR cap and ~260 MB/dispatch scratch spill. So the pass kernel contains NO finalize:
// it reads precomputed m/iv/zb from the global MIV buffer written by caps_fin.

struct __align__(16) PassMem {
    float pose[CG * 16];     //  4.6 KB
    float act[CG];           //  0.3 KB
    float red[4][O_][33];    // 16.9 KB (stride 33: conflict-free)
};

template<bool HASE>
__global__ __launch_bounds__(THREADS, 2) void caps_pass(
    const float* __restrict__ in_act, const float* __restrict__ in_pose,
    const float* __restrict__ W, const float* __restrict__ MIV,
    float* __restrict__ Pout)
{
    __shared__ PassMem sm;
    const int blk = blockIdx.x;
    const int bp = blk >> 2, g = blk & 3;       // G_ = 4
    const int b  = bp / P_,  p = bp % P_;
    const int tid = threadIdx.x;
    const int row0 = (p / 6) * 2, col0 = (p % 6) * 2;

    for (int f = tid; f < CG * 4; f += THREADS) {
        const int fq = g * (CG * 4) + f;
        const int qw = fq >> 7, r = fq & 127;
        const int pix = (row0 + qw / 3) * SIZE_IN + (col0 + qw % 3);
        reinterpret_cast<float4*>(sm.pose)[f] =
            reinterpret_cast<const float4*>(in_pose + (size_t)(b * 196 + pix) * 512)[r];
    }
    for (int idx = tid; idx < CG; idx += THREADS) {
        const int c = g * CG + idx;
        const int qw = c >> 5, ic = c & 31;
        const int pix = (row0 + qw / 3) * SIZE_IN + (col0 + qw % 3);
        sm.act[idx] = in_act[(size_t)(b * 196 + pix) * 32 + ic];
    }
    __syncthreads();

    const int o  = tid & 31;
    const int ci = tid >> 5;

    float m[16], iv[16], zb = 0.f;
    if (HASE) {  // straight register loads, no reduction phase
        const float* mb = MIV + ((size_t)bp * O_ + o) * MIVS;
        const float4* mv = reinterpret_cast<const float4*>(mb);
        float4 a0 = mv[0], a1 = mv[1], a2 = mv[2], a3 = mv[3];
        float4 b0 = mv[4], b1 = mv[5], b2 = mv[6], b3 = mv[7];
        F4_TO_ARR(m, 0, a0) F4_TO_ARR(m, 4, a1) F4_TO_ARR(m, 8, a2) F4_TO_ARR(m, 12, a3)
        F4_TO_ARR(iv, 0, b0) F4_TO_ARR(iv, 4, b1) F4_TO_ARR(iv, 8, b2) F4_TO_ARR(iv, 12, b3)
        zb = mb[32];
    }

    float S0 = 0.f, S1[16], S2[16];
    #pragma unroll
    for (int j = 0; j < 16; ++j) { S1[j] = 0.f; S2[j] = 0.f; }

    const float4* wp0 = reinterpret_cast<const float4*>(W + (size_t)((g * CG + ci) * O_ + o) * 16);
    float4 nw0 = wp0[0], nw1 = wp0[1], nw2 = wp0[2], nw3 = wp0[3];
    const float4* pp0 = reinterpret_cast<const float4*>(&sm.pose[ci * 16]);
    float4 np0 = pp0[0], np1 = pp0[1], np2 = pp0[2], np3 = pp0[3];

    #pragma unroll 2
    for (int t = 0; t < NTG; ++t) {
        const int cl = t * 8 + ci;
        float w[16], q[16];
        F4_TO_ARR(w, 0, nw0) F4_TO_ARR(w, 4, nw1) F4_TO_ARR(w, 8, nw2) F4_TO_ARR(w, 12, nw3)
        F4_TO_ARR(q, 0, np0) F4_TO_ARR(q, 4, np1) F4_TO_ARR(q, 8, np2) F4_TO_ARR(q, 12, np3)
        if (t + 1 < NTG) {
            const int cn = g * CG + cl + 8;
            const float4* wn = reinterpret_cast<const float4*>(W + (size_t)(cn * O_ + o) * 16);
            nw0 = wn[0]; nw1 = wn[1]; nw2 = wn[2]; nw3 = wn[3];
            const float4* pn = reinterpret_cast<const float4*>(&sm.pose[(cl + 8) * 16]);
            np0 = pn[0]; np1 = pn[1]; np2 = pn[2]; np3 = pn[3];
        }

        float v[16];
        #pragma unroll
        for (int i = 0; i < 4; ++i) {
            #pragma unroll
            for (int jj = 0; jj < 4; ++jj) {
                float acc = q[i*4+0] * w[0*4+jj];
                acc = fmaf(q[i*4+1], w[1*4+jj], acc);
                acc = fmaf(q[i*4+2], w[2*4+jj], acc);
                acc = fmaf(q[i*4+3], w[3*4+jj], acc);
                v[i*4+jj] = acc;
            }
        }

        float ws;
        if (HASE) {
            float s = 0.f;
            #pragma unroll
            for (int j = 0; j < 16; ++j) { float d = v[j] - m[j]; s = fmaf(d * d, iv[j], s); }
            float zz = zb - s;
            float mx = red32_max(zz);
            float e = __expf(zz - mx);
            float sum = red32_sum(e);
            ws = (e / sum) * sm.act[cl];
        } else {
            ws = sm.act[cl] * (1.0f / 32.0f);
        }

        S0 += ws;
        #pragma unroll
        for (int j = 0; j < 16; ++j) {
            float t0 = ws * v[j];
            S1[j] += t0;
            S2[j] = fmaf(t0, v[j], S2[j]);
        }
    }

    S0 += __shfl_xor(S0, 32);
    #pragma unroll
    for (int j = 0; j < 16; ++j) {
        S1[j] += __shfl_xor(S1[j], 32);
        S2[j] += __shfl_xor(S2[j], 32);
    }
    if (!(tid & 32)) {
        const int wv = tid >> 6;
        float* r = sm.red[wv][o];
        r[0] = S0;
        #pragma unroll
        for (int j = 0; j < 16; ++j) { r[1 + j] = S1[j]; r[17 + j] = S2[j]; }
    }
    __syncthreads();

    float* slot = Pout + (size_t)(bp * G_ + g) * O_ * 33;
    for (int idx = tid; idx < O_ * 33; idx += THREADS) {
        const int oo = idx / 33, k = idx - oo * 33;
        slot[idx] = sm.red[0][oo][k] + sm.red[1][oo][k] + sm.red[2][oo][k] + sm.red[3][oo][k];
    }
}

// Finalize: reduce the G_ partial slots of each bp.
// LAST=false: write MIV (m, iv, zb) for the next pass. LAST=true: write final outputs.
template<bool LAST>
__global__ __launch_bounds__(THREADS, 2) void caps_fin(
    const float* __restrict__ Pin, const float* __restrict__ beta_a,
    const float* __restrict__ beta_v, float* __restrict__ MIV,
    float* __restrict__ out, float lambda)
{
    const int bp = blockIdx.x;
    const int tid = threadIdx.x;
    const float* base = Pin + (size_t)bp * G_ * O_ * 33;
    #pragma unroll
    for (int half = 0; half < 2; ++half) {
        const int of = (tid >> 4) + half * 16, jf = tid & 15;
        float s0 = 0.f, s1 = 0.f, s2 = 0.f;
        #pragma unroll
        for (int gg = 0; gg < G_; ++gg) {
            const float* r = base + ((size_t)gg * O_ + of) * 33;
            s0 += r[0]; s1 += r[1 + jf]; s2 += r[17 + jf];
        }
        float denom = s0 + EPS;
        float mj = s1 / denom;
        float varn = fmaxf(s2 - 2.f * mj * s1 + mj * mj * s0, 0.f);
        float sd = sqrtf(varn / denom);
        float sumlog = red16_sum(__logf(sd + EPS));
        if (!LAST) {
            float* mb = MIV + ((size_t)bp * O_ + of) * MIVS;
            mb[jf] = mj;
            mb[16 + jf] = 1.f / fmaf(2.f * sd, sd, EPS);
            if (jf == 0) {
                float cost = fmaf(16.f, beta_v[of], s0 * sumlog);
                float oact = 1.f / (1.f + __expf(-(lambda * (beta_a[of] - cost))));
                mb[32] = __logf(oact + EPS) - sumlog;
            }
        } else {
            out[NBP * O_ + ((size_t)bp * O_ + of) * 16 + jf] = mj;
            if (jf == 0) {
                float cost = fmaf(16.f, beta_v[of], s0 * sumlog);
                float oact = 1.f / (1.f + __expf(-(lambda * (beta_a[of] - cost))));
                out[bp * O_ + of] = oact;
            }
        }
    }
}

// ===================== PATH B: fused single kernel (round 8, proven, 91 us) =====================
struct __align__(16) SMem {
    float pose[Cc * 16];
    float act[Cc];
    float red[4][O_][33];
    float mean[O_][17];
    float iv[O_][17];
    float zb[O_];
};

template<bool HASE, bool LAST>
__device__ __forceinline__ void em_pass(
    SMem& sm, const float* __restrict__ W,
    const float* __restrict__ beta_a, const float* __restrict__ beta_v,
    float lambda, int bp, float* __restrict__ out)
{
    const int tid = threadIdx.x;
    const int o  = tid & 31;
    const int ci = tid >> 5;

    float m[16], iv[16], zb = 0.f;
    if (HASE) {
        #pragma unroll
        for (int j = 0; j < 16; ++j) { m[j] = sm.mean[o][j]; iv[j] = sm.iv[o][j]; }
        zb = sm.zb[o];
    }

    float S0 = 0.f, S1[16], S2[16];
    #pragma unroll
    for (int j = 0; j < 16; ++j) { S1[j] = 0.f; S2[j] = 0.f; }

    const float4* wp0 = reinterpret_cast<const float4*>(W + (size_t)(ci * O_ + o) * 16);
    float4 nw0 = wp0[0], nw1 = wp0[1], nw2 = wp0[2], nw3 = wp0[3];
    const float4* pp0 = reinterpret_cast<const float4*>(&sm.pose[ci * 16]);
    float4 np0 = pp0[0], np1 = pp0[1], np2 = pp0[2], np3 = pp0[3];

    #pragma unroll 2
    for (int t = 0; t < 36; ++t) {
        const int c = t * 8 + ci;
        float w[16], q[16];
        F4_TO_ARR(w, 0, nw0) F4_TO_ARR(w, 4, nw1) F4_TO_ARR(w, 8, nw2) F4_TO_ARR(w, 12, nw3)
        F4_TO_ARR(q, 0, np0) F4_TO_ARR(q, 4, np1) F4_TO_ARR(q, 8, np2) F4_TO_ARR(q, 12, np3)
        if (t + 1 < 36) {
            const int cn = c + 8;
            const float4* wn = reinterpret_cast<const float4*>(W + (size_t)(cn * O_ + o) * 16);
            nw0 = wn[0]; nw1 = wn[1]; nw2 = wn[2]; nw3 = wn[3];
            const float4* pn = reinterpret_cast<const float4*>(&sm.pose[cn * 16]);
            np0 = pn[0]; np1 = pn[1]; np2 = pn[2]; np3 = pn[3];
        }

        float v[16];
        #pragma unroll
        for (int i = 0; i < 4; ++i) {
            #pragma unroll
            for (int jj = 0; jj < 4; ++jj) {
                float acc = q[i*4+0] * w[0*4+jj];
                acc = fmaf(q[i*4+1], w[1*4+jj], acc);
                acc = fmaf(q[i*4+2], w[2*4+jj], acc);
                acc = fmaf(q[i*4+3], w[3*4+jj], acc);
                v[i*4+jj] = acc;
            }
        }

        float ws;
        if (HASE) {
            float s = 0.f;
            #pragma unroll
            for (int j = 0; j < 16; ++j) { float d = v[j] - m[j]; s = fmaf(d * d, iv[j], s); }
            float zz = zb - s;
            float mx = red32_max(zz);
            float e = __expf(zz - mx);
            float sum = red32_sum(e);
            ws = (e / sum) * sm.act[c];
        } else {
            ws = sm.act[c] * (1.0f / 32.0f);
        }

        S0 += ws;
        #pragma unroll
        for (int j = 0; j < 16; ++j) {
            float t0 = ws * v[j];
            S1[j] += t0;
            S2[j] = fmaf(t0, v[j], S2[j]);
        }
    }

    S0 += __shfl_xor(S0, 32);
    #pragma unroll
    for (int j = 0; j < 16; ++j) {
        S1[j] += __shfl_xor(S1[j], 32);
        S2[j] += __shfl_xor(S2[j], 32);
    }
    if (!(tid & 32)) {
        const int wv = tid >> 6;
        float* r = sm.red[wv][o];
        r[0] = S0;
        #pragma unroll
        for (int j = 0; j < 16; ++j) { r[1 + j] = S1[j]; r[17 + j] = S2[j]; }
    }
    __syncthreads();

    #pragma unroll
    for (int half = 0; half < 2; ++half) {
        const int of = (tid >> 4) + half * 16, jf = tid & 15;
        const float* r0 = sm.red[0][of];
        const float* r1 = sm.red[1][of];
        const float* r2 = sm.red[2][of];
        const float* r3 = sm.red[3][of];
        float s0 = r0[0] + r1[0] + r2[0] + r3[0];
        float s1 = r0[1+jf] + r1[1+jf] + r2[1+jf] + r3[1+jf];
        float s2 = r0[17+jf] + r1[17+jf] + r2[17+jf] + r3[17+jf];
        float denom = s0 + EPS;
        float mj = s1 / denom;
        float varn = fmaxf(s2 - 2.f * mj * s1 + mj * mj * s0, 0.f);
        float sd = sqrtf(varn / denom);
        float sumlog = red16_sum(__logf(sd + EPS));
        if (!LAST) {
            sm.mean[of][jf] = mj;
            sm.iv[of][jf] = 1.f / fmaf(2.f * sd, sd, EPS);
            if (jf == 0) {
                float cost = fmaf(16.f, beta_v[of], s0 * sumlog);
                float oact = 1.f / (1.f + __expf(-(lambda * (beta_a[of] - cost))));
                sm.zb[of] = __logf(oact + EPS) - sumlog;
            }
        } else {
            out[NBP * O_ + ((size_t)bp * O_ + of) * 16 + jf] = mj;
            if (jf == 0) {
                float cost = fmaf(16.f, beta_v[of], s0 * sumlog);
                float oact = 1.f / (1.f + __expf(-(lambda * (beta_a[of] - cost))));
                out[bp * O_ + of] = oact;
            }
        }
    }
    __syncthreads();
}

__global__ __launch_bounds__(THREADS, 2) void convcaps_fused(
    const float* __restrict__ in_act, const float* __restrict__ in_pose,
    const float* __restrict__ W, const float* __restrict__ beta_a,
    const float* __restrict__ beta_v, float* __restrict__ out)
{
    __shared__ SMem sm;
    const int bp = blockIdx.x;
    const int b  = bp / P_;
    const int p  = bp % P_;
    const int tid = threadIdx.x;
    const int row0 = (p / 6) * 2, col0 = (p % 6) * 2;

    for (int f = tid; f < 9 * 128; f += THREADS) {
        const int qw = f >> 7, r = f & 127;
        const int pix = (row0 + qw / 3) * SIZE_IN + (col0 + qw % 3);
        reinterpret_cast<float4*>(sm.pose)[qw * 128 + r] =
            reinterpret_cast<const float4*>(in_pose + (size_t)(b * 196 + pix) * 512)[r];
    }
    for (int idx = tid; idx < Cc; idx += THREADS) {
        const int qw = idx >> 5, ic = idx & 31;
        const int pix = (row0 + qw / 3) * SIZE_IN + (col0 + qw % 3);
        sm.act[idx] = in_act[(size_t)(b * 196 + pix) * 32 + ic];
    }
    __syncthreads();

    em_pass<false, false>(sm, W, beta_a, beta_v, 0.0f,      bp, out);
    em_pass<true,  false>(sm, W, beta_a, beta_v, 0.0005f,   bp, out);
    em_pass<true,  true >(sm, W, beta_a, beta_v, 0.000975f, bp, out);
}

// ============================ dispatch ============================
extern "C" void kernel_launch(void* const* d_in, const int* in_sizes, int n_in,
                              void* d_out, int out_size, void* d_ws, size_t ws_size,
                              hipStream_t stream) {
    const float* in_act  = (const float*)d_in[0];
    const float* in_pose = (const float*)d_in[1];
    const float* W       = (const float*)d_in[2];
    const float* beta_a  = (const float*)d_in[3];
    const float* beta_v  = (const float*)d_in[4];
    float* out = (float*)d_out;

    const size_t p_elems   = (size_t)NBP * G_ * O_ * 33;   // 1,216,512 floats
    const size_t miv_elems = (size_t)NBP * O_ * MIVS;      //   331,776 floats
    const size_t need = (p_elems + miv_elems) * sizeof(float);   // ~6.2 MB

    if (ws_size >= need) {
        float* P   = (float*)d_ws;
        float* MIV = P + p_elems;
        dim3 gp(NBP * G_), gf(NBP), blk(THREADS);
        // iter 0: M-step (rr uniform) -> fin with lambda_0 = 0 (act = 0.5)
        caps_pass<false><<<gp, blk, 0, stream>>>(in_act, in_pose, W, nullptr, P);
        caps_fin<false><<<gf, blk, 0, stream>>>(P, beta_a, beta_v, MIV, nullptr, 0.0f);
        // iter 1: E+M -> fin with lambda_1 = 0.01*(1-0.95) = 5e-4
        caps_pass<true><<<gp, blk, 0, stream>>>(in_act, in_pose, W, MIV, P);
        caps_fin<false><<<gf, blk, 0, stream>>>(P, beta_a, beta_v, MIV, nullptr, 0.0005f);
        // iter 2: E+M -> outputs with lambda_2 = 0.01*(1-0.95^2) = 9.75e-4
        caps_pass<true><<<gp, blk, 0, stream>>>(in_act, in_pose, W, MIV, P);
        caps_fin<true><<<gf, blk, 0, stream>>>(P, beta_a, beta_v, nullptr, out, 0.000975f);
    } else {
        convcaps_fused<<<dim3(NBP), dim3(THREADS), 0, stream>>>(
            in_act, in_pose, W, beta_a, beta_v, out);
    }
}

// Round 15
// 146.306 us; speedup vs baseline: 2.3441x; 2.3441x over previous
//
#include <hip/hip_runtime.h>
#include <math.h>

#define EPS 1e-7f

constexpr int SIZE_IN = 14;
constexpr int P_  = 36;   // 6x6 parent positions
constexpr int Cc  = 288;  // children per parent (3*3*32)
constexpr int O_  = 32;   // output capsules
constexpr int G_  = 4;    // child groups per parent (grid-split path)
constexpr int CG  = Cc / G_;   // 72 children per group
constexpr int NTG = CG / 8;    // 9 children per thread in split path
constexpr int THREADS = 256;
constexpr int NBP = 8 * P_;    // 288 (b,p) pairs
constexpr int MIVS = 36;       // MIV stride per o: m[16]@0, iv[16]@16, zb@32

// ---- DPP-based butterfly reductions (validated round 8: -17% vs __shfl_xor) ----
template<int CTRL>
__device__ __forceinline__ float dppf(float x) {
    int xi = __builtin_bit_cast(int, x);
    return __builtin_bit_cast(float,
        __builtin_amdgcn_update_dpp(xi, xi, CTRL, 0xf, 0xf, true));
}
__device__ __forceinline__ float swz16(float x) {
    return __builtin_bit_cast(float,
        __builtin_amdgcn_ds_swizzle(__builtin_bit_cast(int, x), 0x401F));
}
__device__ __forceinline__ float red32_max(float x) {
    x = fmaxf(x, dppf<0xB1>(x));
    x = fmaxf(x, dppf<0x4E>(x));
    x = fmaxf(x, dppf<0x141>(x));
    x = fmaxf(x, dppf<0x140>(x));
    x = fmaxf(x, swz16(x));
    return x;
}
__device__ __forceinline__ float red32_sum(float x) {
    x += dppf<0xB1>(x);
    x += dppf<0x4E>(x);
    x += dppf<0x141>(x);
    x += dppf<0x140>(x);
    x += swz16(x);
    return x;
}
__device__ __forceinline__ float red16_sum(float x) {  // within 16-lane groups
    x += dppf<0xB1>(x);
    x += dppf<0x4E>(x);
    x += dppf<0x141>(x);
    x += dppf<0x140>(x);
    return x;
}

#define F4_TO_ARR(dst, off, f4) \
    dst[(off)+0] = (f4).x; dst[(off)+1] = (f4).y; dst[(off)+2] = (f4).z; dst[(off)+3] = (f4).w;

// ===================== PATH A: grid-split pipeline (lean pass + separate fin) =====================
// SPILL DIAGNOSIS (r10/r11): 9-iter child loop w/ "#pragma unroll 2" -> LLVM effectively
// fully unrolls/hoists prefetch loads -> pressure blows past target -> ~915 B/thread scratch.
// 36-iter loops (r1/r8) never spilled. Fix: unroll 1 + launch_bounds(,1) + LDS-staged MIV.

struct __align__(16) PassMem {
    float pose[CG * 16];     //  4.6 KB
    float act[CG];           //  0.3 KB
    float red[4][O_][33];    // 16.9 KB (stride 33: conflict-free)
    float miv[O_][33];       //  4.2 KB m/iv/zb staged from global (lane o reads row o: conflict-free)
};

template<bool HASE>
__global__ __launch_bounds__(THREADS, 1) void caps_pass(
    const float* __restrict__ in_act, const float* __restrict__ in_pose,
    const float* __restrict__ W, const float* __restrict__ MIV,
    float* __restrict__ Pout)
{
    __shared__ PassMem sm;
    const int blk = blockIdx.x;
    const int bp = blk >> 2, g = blk & 3;       // G_ = 4
    const int b  = bp / P_,  p = bp % P_;
    const int tid = threadIdx.x;
    const int row0 = (p / 6) * 2, col0 = (p % 6) * 2;

    for (int f = tid; f < CG * 4; f += THREADS) {
        const int fq = g * (CG * 4) + f;
        const int qw = fq >> 7, r = fq & 127;
        const int pix = (row0 + qw / 3) * SIZE_IN + (col0 + qw % 3);
        reinterpret_cast<float4*>(sm.pose)[f] =
            reinterpret_cast<const float4*>(in_pose + (size_t)(b * 196 + pix) * 512)[r];
    }
    for (int idx = tid; idx < CG; idx += THREADS) {
        const int c = g * CG + idx;
        const int qw = c >> 5, ic = c & 31;
        const int pix = (row0 + qw / 3) * SIZE_IN + (col0 + qw % 3);
        sm.act[idx] = in_act[(size_t)(b * 196 + pix) * 32 + ic];
    }
    if (HASE) {  // stage m/iv/zb into LDS (r8's proven no-spill source pattern)
        const float* mb = MIV + (size_t)bp * O_ * MIVS;
        for (int idx = tid; idx < O_ * 33; idx += THREADS) {
            const int oo = idx / 33, k = idx - oo * 33;
            sm.miv[oo][k] = mb[oo * MIVS + k];
        }
    }
    __syncthreads();

    const int o  = tid & 31;
    const int ci = tid >> 5;

    float m[16], iv[16], zb = 0.f;
    if (HASE) {
        #pragma unroll
        for (int j = 0; j < 16; ++j) { m[j] = sm.miv[o][j]; iv[j] = sm.miv[o][16 + j]; }
        zb = sm.miv[o][32];
    }

    float S0 = 0.f, S1[16], S2[16];
    #pragma unroll
    for (int j = 0; j < 16; ++j) { S1[j] = 0.f; S2[j] = 0.f; }

    const float4* wp0 = reinterpret_cast<const float4*>(W + (size_t)((g * CG + ci) * O_ + o) * 16);
    float4 nw0 = wp0[0], nw1 = wp0[1], nw2 = wp0[2], nw3 = wp0[3];
    const float4* pp0 = reinterpret_cast<const float4*>(&sm.pose[ci * 16]);
    float4 np0 = pp0[0], np1 = pp0[1], np2 = pp0[2], np3 = pp0[3];

    #pragma unroll 1   // 9-iter loop MUST NOT unroll (full-unroll => register blowup, r10/r11)
    for (int t = 0; t < NTG; ++t) {
        const int cl = t * 8 + ci;
        float w[16], q[16];
        F4_TO_ARR(w, 0, nw0) F4_TO_ARR(w, 4, nw1) F4_TO_ARR(w, 8, nw2) F4_TO_ARR(w, 12, nw3)
        F4_TO_ARR(q, 0, np0) F4_TO_ARR(q, 4, np1) F4_TO_ARR(q, 8, np2) F4_TO_ARR(q, 12, np3)
        if (t + 1 < NTG) {
            const int cn = g * CG + cl + 8;
            const float4* wn = reinterpret_cast<const float4*>(W + (size_t)(cn * O_ + o) * 16);
            nw0 = wn[0]; nw1 = wn[1]; nw2 = wn[2]; nw3 = wn[3];
            const float4* pn = reinterpret_cast<const float4*>(&sm.pose[(cl + 8) * 16]);
            np0 = pn[0]; np1 = pn[1]; np2 = pn[2]; np3 = pn[3];
        }

        float v[16];
        #pragma unroll
        for (int i = 0; i < 4; ++i) {
            #pragma unroll
            for (int jj = 0; jj < 4; ++jj) {
                float acc = q[i*4+0] * w[0*4+jj];
                acc = fmaf(q[i*4+1], w[1*4+jj], acc);
                acc = fmaf(q[i*4+2], w[2*4+jj], acc);
                acc = fmaf(q[i*4+3], w[3*4+jj], acc);
                v[i*4+jj] = acc;
            }
        }

        float ws;
        if (HASE) {
            float s = 0.f;
            #pragma unroll
            for (int j = 0; j < 16; ++j) { float d = v[j] - m[j]; s = fmaf(d * d, iv[j], s); }
            float zz = zb - s;
            float mx = red32_max(zz);
            float e = __expf(zz - mx);
            float sum = red32_sum(e);
            ws = (e / sum) * sm.act[cl];
        } else {
            ws = sm.act[cl] * (1.0f / 32.0f);
        }

        S0 += ws;
        #pragma unroll
        for (int j = 0; j < 16; ++j) {
            float t0 = ws * v[j];
            S1[j] += t0;
            S2[j] = fmaf(t0, v[j], S2[j]);
        }
    }

    S0 += __shfl_xor(S0, 32);
    #pragma unroll
    for (int j = 0; j < 16; ++j) {
        S1[j] += __shfl_xor(S1[j], 32);
        S2[j] += __shfl_xor(S2[j], 32);
    }
    if (!(tid & 32)) {
        const int wv = tid >> 6;
        float* r = sm.red[wv][o];
        r[0] = S0;
        #pragma unroll
        for (int j = 0; j < 16; ++j) { r[1 + j] = S1[j]; r[17 + j] = S2[j]; }
    }
    __syncthreads();

    float* slot = Pout + (size_t)(bp * G_ + g) * O_ * 33;
    for (int idx = tid; idx < O_ * 33; idx += THREADS) {
        const int oo = idx / 33, k = idx - oo * 33;
        slot[idx] = sm.red[0][oo][k] + sm.red[1][oo][k] + sm.red[2][oo][k] + sm.red[3][oo][k];
    }
}

// Finalize: reduce the G_ partial slots of each bp.
// LAST=false: write MIV (m, iv, zb) for the next pass. LAST=true: write final outputs.
template<bool LAST>
__global__ __launch_bounds__(THREADS, 2) void caps_fin(
    const float* __restrict__ Pin, const float* __restrict__ beta_a,
    const float* __restrict__ beta_v, float* __restrict__ MIV,
    float* __restrict__ out, float lambda)
{
    const int bp = blockIdx.x;
    const int tid = threadIdx.x;
    const float* base = Pin + (size_t)bp * G_ * O_ * 33;
    #pragma unroll
    for (int half = 0; half < 2; ++half) {
        const int of = (tid >> 4) + half * 16, jf = tid & 15;
        float s0 = 0.f, s1 = 0.f, s2 = 0.f;
        #pragma unroll
        for (int gg = 0; gg < G_; ++gg) {
            const float* r = base + ((size_t)gg * O_ + of) * 33;
            s0 += r[0]; s1 += r[1 + jf]; s2 += r[17 + jf];
        }
        float denom = s0 + EPS;
        float mj = s1 / denom;
        float varn = fmaxf(s2 - 2.f * mj * s1 + mj * mj * s0, 0.f);
        float sd = sqrtf(varn / denom);
        float sumlog = red16_sum(__logf(sd + EPS));
        if (!LAST) {
            float* mb = MIV + ((size_t)bp * O_ + of) * MIVS;
            mb[jf] = mj;
            mb[16 + jf] = 1.f / fmaf(2.f * sd, sd, EPS);
            if (jf == 0) {
                float cost = fmaf(16.f, beta_v[of], s0 * sumlog);
                float oact = 1.f / (1.f + __expf(-(lambda * (beta_a[of] - cost))));
                mb[32] = __logf(oact + EPS) - sumlog;
            }
        } else {
            out[NBP * O_ + ((size_t)bp * O_ + of) * 16 + jf] = mj;
            if (jf == 0) {
                float cost = fmaf(16.f, beta_v[of], s0 * sumlog);
                float oact = 1.f / (1.f + __expf(-(lambda * (beta_a[of] - cost))));
                out[bp * O_ + of] = oact;
            }
        }
    }
}

// ===================== PATH B: fused single kernel (round 8, proven, 91 us) =====================
struct __align__(16) SMem {
    float pose[Cc * 16];
    float act[Cc];
    float red[4][O_][33];
    float mean[O_][17];
    float iv[O_][17];
    float zb[O_];
};

template<bool HASE, bool LAST>
__device__ __forceinline__ void em_pass(
    SMem& sm, const float* __restrict__ W,
    const float* __restrict__ beta_a, const float* __restrict__ beta_v,
    float lambda, int bp, float* __restrict__ out)
{
    const int tid = threadIdx.x;
    const int o  = tid & 31;
    const int ci = tid >> 5;

    float m[16], iv[16], zb = 0.f;
    if (HASE) {
        #pragma unroll
        for (int j = 0; j < 16; ++j) { m[j] = sm.mean[o][j]; iv[j] = sm.iv[o][j]; }
        zb = sm.zb[o];
    }

    float S0 = 0.f, S1[16], S2[16];
    #pragma unroll
    for (int j = 0; j < 16; ++j) { S1[j] = 0.f; S2[j] = 0.f; }

    const float4* wp0 = reinterpret_cast<const float4*>(W + (size_t)(ci * O_ + o) * 16);
    float4 nw0 = wp0[0], nw1 = wp0[1], nw2 = wp0[2], nw3 = wp0[3];
    const float4* pp0 = reinterpret_cast<const float4*>(&sm.pose[ci * 16]);
    float4 np0 = pp0[0], np1 = pp0[1], np2 = pp0[2], np3 = pp0[3];

    #pragma unroll 2
    for (int t = 0; t < 36; ++t) {
        const int c = t * 8 + ci;
        float w[16], q[16];
        F4_TO_ARR(w, 0, nw0) F4_TO_ARR(w, 4, nw1) F4_TO_ARR(w, 8, nw2) F4_TO_ARR(w, 12, nw3)
        F4_TO_ARR(q, 0, np0) F4_TO_ARR(q, 4, np1) F4_TO_ARR(q, 8, np2) F4_TO_ARR(q, 12, np3)
        if (t + 1 < 36) {
            const int cn = c + 8;
            const float4* wn = reinterpret_cast<const float4*>(W + (size_t)(cn * O_ + o) * 16);
            nw0 = wn[0]; nw1 = wn[1]; nw2 = wn[2]; nw3 = wn[3];
            const float4* pn = reinterpret_cast<const float4*>(&sm.pose[cn * 16]);
            np0 = pn[0]; np1 = pn[1]; np2 = pn[2]; np3 = pn[3];
        }

        float v[16];
        #pragma unroll
        for (int i = 0; i < 4; ++i) {
            #pragma unroll
            for (int jj = 0; jj < 4; ++jj) {
                float acc = q[i*4+0] * w[0*4+jj];
                acc = fmaf(q[i*4+1], w[1*4+jj], acc);
                acc = fmaf(q[i*4+2], w[2*4+jj], acc);
                acc = fmaf(q[i*4+3], w[3*4+jj], acc);
                v[i*4+jj] = acc;
            }
        }

        float ws;
        if (HASE) {
            float s = 0.f;
            #pragma unroll
            for (int j = 0; j < 16; ++j) { float d = v[j] - m[j]; s = fmaf(d * d, iv[j], s); }
            float zz = zb - s;
            float mx = red32_max(zz);
            float e = __expf(zz - mx);
            float sum = red32_sum(e);
            ws = (e / sum) * sm.act[c];
        } else {
            ws = sm.act[c] * (1.0f / 32.0f);
        }

        S0 += ws;
        #pragma unroll
        for (int j = 0; j < 16; ++j) {
            float t0 = ws * v[j];
            S1[j] += t0;
            S2[j] = fmaf(t0, v[j], S2[j]);
        }
    }

    S0 += __shfl_xor(S0, 32);
    #pragma unroll
    for (int j = 0; j < 16; ++j) {
        S1[j] += __shfl_xor(S1[j], 32);
        S2[j] += __shfl_xor(S2[j], 32);
    }
    if (!(tid & 32)) {
        const int wv = tid >> 6;
        float* r = sm.red[wv][o];
        r[0] = S0;
        #pragma unroll
        for (int j = 0; j < 16; ++j) { r[1 + j] = S1[j]; r[17 + j] = S2[j]; }
    }
    __syncthreads();

    #pragma unroll
    for (int half = 0; half < 2; ++half) {
        const int of = (tid >> 4) + half * 16, jf = tid & 15;
        const float* r0 = sm.red[0][of];
        const float* r1 = sm.red[1][of];
        const float* r2 = sm.red[2][of];
        const float* r3 = sm.red[3][of];
        float s0 = r0[0] + r1[0] + r2[0] + r3[0];
        float s1 = r0[1+jf] + r1[1+jf] + r2[1+jf] + r3[1+jf];
        float s2 = r0[17+jf] + r1[17+jf] + r2[17+jf] + r3[17+jf];
        float denom = s0 + EPS;
        float mj = s1 / denom;
        float varn = fmaxf(s2 - 2.f * mj * s1 + mj * mj * s0, 0.f);
        float sd = sqrtf(varn / denom);
        float sumlog = red16_sum(__logf(sd + EPS));
        if (!LAST) {
            sm.mean[of][jf] = mj;
            sm.iv[of][jf] = 1.f / fmaf(2.f * sd, sd, EPS);
            if (jf == 0) {
                float cost = fmaf(16.f, beta_v[of], s0 * sumlog);
                float oact = 1.f / (1.f + __expf(-(lambda * (beta_a[of] - cost))));
                sm.zb[of] = __logf(oact + EPS) - sumlog;
            }
        } else {
            out[NBP * O_ + ((size_t)bp * O_ + of) * 16 + jf] = mj;
            if (jf == 0) {
                float cost = fmaf(16.f, beta_v[of], s0 * sumlog);
                float oact = 1.f / (1.f + __expf(-(lambda * (beta_a[of] - cost))));
                out[bp * O_ + of] = oact;
            }
        }
    }
    __syncthreads();
}

__global__ __launch_bounds__(THREADS, 2) void convcaps_fused(
    const float* __restrict__ in_act, const float* __restrict__ in_pose,
    const float* __restrict__ W, const float* __restrict__ beta_a,
    const float* __restrict__ beta_v, float* __restrict__ out)
{
    __shared__ SMem sm;
    const int bp = blockIdx.x;
    const int b  = bp / P_;
    const int p  = bp % P_;
    const int tid = threadIdx.x;
    const int row0 = (p / 6) * 2, col0 = (p % 6) * 2;

    for (int f = tid; f < 9 * 128; f += THREADS) {
        const int qw = f >> 7, r = f & 127;
        const int pix = (row0 + qw / 3) * SIZE_IN + (col0 + qw % 3);
        reinterpret_cast<float4*>(sm.pose)[qw * 128 + r] =
            reinterpret_cast<const float4*>(in_pose + (size_t)(b * 196 + pix) * 512)[r];
    }
    for (int idx = tid; idx < Cc; idx += THREADS) {
        const int qw = idx >> 5, ic = idx & 31;
        const int pix = (row0 + qw / 3) * SIZE_IN + (col0 + qw % 3);
        sm.act[idx] = in_act[(size_t)(b * 196 + pix) * 32 + ic];
    }
    __syncthreads();

    em_pass<false, false>(sm, W, beta_a, beta_v, 0.0f,      bp, out);
    em_pass<true,  false>(sm, W, beta_a, beta_v, 0.0005f,   bp, out);
    em_pass<true,  true >(sm, W, beta_a, beta_v, 0.000975f, bp, out);
}

// ============================ dispatch ============================
extern "C" void kernel_launch(void* const* d_in, const int* in_sizes, int n_in,
                              void* d_out, int out_size, void* d_ws, size_t ws_size,
                              hipStream_t stream) {
    const float* in_act  = (const float*)d_in[0];
    const float* in_pose = (const float*)d_in[1];
    const float* W       = (const float*)d_in[2];
    const float* beta_a  = (const float*)d_in[3];
    const float* beta_v  = (const float*)d_in[4];
    float* out = (float*)d_out;

    const size_t p_elems   = (size_t)NBP * G_ * O_ * 33;   // 1,216,512 floats
    const size_t miv_elems = (size_t)NBP * O_ * MIVS;      //   331,776 floats
    const size_t need = (p_elems + miv_elems) * sizeof(float);   // ~6.2 MB

    if (ws_size >= need) {
        float* P   = (float*)d_ws;
        float* MIV = P + p_elems;
        dim3 gp(NBP * G_), gf(NBP), blk(THREADS);
        // iter 0: M-step (rr uniform) -> fin with lambda_0 = 0 (act = 0.5)
        caps_pass<false><<<gp, blk, 0, stream>>>(in_act, in_pose, W, nullptr, P);
        caps_fin<false><<<gf, blk, 0, stream>>>(P, beta_a, beta_v, MIV, nullptr, 0.0f);
        // iter 1: E+M -> fin with lambda_1 = 0.01*(1-0.95) = 5e-4
        caps_pass<true><<<gp, blk, 0, stream>>>(in_act, in_pose, W, MIV, P);
        caps_fin<false><<<gf, blk, 0, stream>>>(P, beta_a, beta_v, MIV, nullptr, 0.0005f);
        // iter 2: E+M -> outputs with lambda_2 = 0.01*(1-0.95^2) = 9.75e-4
        caps_pass<true><<<gp, blk, 0, stream>>>(in_act, in_pose, W, MIV, P);
        caps_fin<true><<<gf, blk, 0, stream>>>(P, beta_a, beta_v, nullptr, out, 0.000975f);
    } else {
        convcaps_fused<<<dim3(NBP), dim3(THREADS), 0, stream>>>(
            in_act, in_pose, W, beta_a, beta_v, out);
    }
}

// Round 16
// 143.494 us; speedup vs baseline: 2.3900x; 1.0196x over previous
//
#include <hip/hip_runtime.h>
#include <math.h>

#define EPS 1e-7f

constexpr int SIZE_IN = 14;
constexpr int P_  = 36;   // 6x6 parent positions
constexpr int Cc  = 288;  // children per parent (3*3*32)
constexpr int O_  = 32;   // output capsules
constexpr int G_  = 2;    // child groups per parent (persistent path)
constexpr int CG  = Cc / G_;   // 144 children per group
constexpr int NTG = CG / 8;    // 18 children per thread
constexpr int THREADS = 256;
constexpr int NBP = 8 * P_;    // 288 (b,p) pairs
constexpr int NBLK = NBP * G_; // 576 blocks (persistent grid)

// ---- DPP-based butterfly reductions (validated round 8: -17% vs __shfl_xor) ----
template<int CTRL>
__device__ __forceinline__ float dppf(float x) {
    int xi = __builtin_bit_cast(int, x);
    return __builtin_bit_cast(float,
        __builtin_amdgcn_update_dpp(xi, xi, CTRL, 0xf, 0xf, true));
}
__device__ __forceinline__ float swz16(float x) {
    return __builtin_bit_cast(float,
        __builtin_amdgcn_ds_swizzle(__builtin_bit_cast(int, x), 0x401F));
}
__device__ __forceinline__ float red32_max(float x) {
    x = fmaxf(x, dppf<0xB1>(x));
    x = fmaxf(x, dppf<0x4E>(x));
    x = fmaxf(x, dppf<0x141>(x));
    x = fmaxf(x, dppf<0x140>(x));
    x = fmaxf(x, swz16(x));
    return x;
}
__device__ __forceinline__ float red32_sum(float x) {
    x += dppf<0xB1>(x);
    x += dppf<0x4E>(x);
    x += dppf<0x141>(x);
    x += dppf<0x140>(x);
    x += swz16(x);
    return x;
}
__device__ __forceinline__ float red16_sum(float x) {  // within 16-lane groups
    x += dppf<0xB1>(x);
    x += dppf<0x4E>(x);
    x += dppf<0x141>(x);
    x += dppf<0x140>(x);
    return x;
}

#define F4_TO_ARR(dst, off, f4) \
    dst[(off)+0] = (f4).x; dst[(off)+1] = (f4).y; dst[(off)+2] = (f4).z; dst[(off)+3] = (f4).w;

// ---- software grid barrier (device-scope). SAFE ONLY when all blocks co-resident;
// residency is verified at launch via hipOccupancyMaxActiveBlocksPerMultiprocessor. ----
__device__ __forceinline__ void gridbar(unsigned* ctr) {
    __threadfence();                 // release: flush this block's stores to device scope
    __syncthreads();
    if (threadIdx.x == 0) {
        __atomic_fetch_add(ctr, 1u, __ATOMIC_RELAXED);
        while (__atomic_load_n(ctr, __ATOMIC_RELAXED) < (unsigned)NBLK)
            __builtin_amdgcn_s_sleep(8);
    }
    __syncthreads();
    __threadfence();                 // acquire: invalidate stale cached lines
}

// ===================== persistent-kernel path =====================
// P slot layout: P[((bp*G_ + g)*O_ + o)*33 + k], k: 0=S0, 1..16=S1, 17..32=S2
struct __align__(16) AllMem {
    float pose[CG * 16];     //  9.2 KB (staged ONCE, reused by all 3 passes)
    float act[CG];           //  0.6 KB
    float red[4][O_][33];    // 16.9 KB (stride 33: conflict-free)
    float miv[O_][33];       //  4.2 KB m[16],iv[16],zb per o
};                           // ~31 KB -> 4 blocks/CU (VGPR-capped), 1024 >= 576 resident

// Finalize the G_ partial slots of bp. LAST=false -> write sm.miv; LAST=true -> write out.
template<bool LAST>
__device__ __forceinline__ void fin_phase(
    AllMem& sm, const float* __restrict__ Pin, const float* __restrict__ beta_a,
    const float* __restrict__ beta_v, float lambda, int bp, float* __restrict__ out)
{
    const int tid = threadIdx.x;
    const float* base = Pin + (size_t)bp * G_ * O_ * 33;
    #pragma unroll
    for (int half = 0; half < 2; ++half) {
        const int of = (tid >> 4) + half * 16, jf = tid & 15;
        float s0 = 0.f, s1 = 0.f, s2 = 0.f;
        #pragma unroll
        for (int gg = 0; gg < G_; ++gg) {
            const float* r = base + ((size_t)gg * O_ + of) * 33;
            s0 += r[0]; s1 += r[1 + jf]; s2 += r[17 + jf];
        }
        float denom = s0 + EPS;
        float mj = s1 / denom;
        float varn = fmaxf(s2 - 2.f * mj * s1 + mj * mj * s0, 0.f);
        float sd = sqrtf(varn / denom);
        float sumlog = red16_sum(__logf(sd + EPS));
        if (!LAST) {
            sm.miv[of][jf] = mj;
            sm.miv[of][16 + jf] = 1.f / fmaf(2.f * sd, sd, EPS);
            if (jf == 0) {
                float cost = fmaf(16.f, beta_v[of], s0 * sumlog);
                float oact = 1.f / (1.f + __expf(-(lambda * (beta_a[of] - cost))));
                sm.miv[of][32] = __logf(oact + EPS) - sumlog;
            }
        } else {
            out[NBP * O_ + ((size_t)bp * O_ + of) * 16 + jf] = mj;
            if (jf == 0) {
                float cost = fmaf(16.f, beta_v[of], s0 * sumlog);
                float oact = 1.f / (1.f + __expf(-(lambda * (beta_a[of] - cost))));
                out[bp * O_ + of] = oact;
            }
        }
    }
}

__global__ __launch_bounds__(THREADS, 2) void caps_all(
    const float* __restrict__ in_act, const float* __restrict__ in_pose,
    const float* __restrict__ W, const float* __restrict__ beta_a,
    const float* __restrict__ beta_v, float* __restrict__ out,
    float* __restrict__ P1, float* __restrict__ P2, unsigned* __restrict__ bars)
{
    __shared__ AllMem sm;
    const int blk = blockIdx.x;
    const int bp = blk >> 1, g = blk & 1;       // G_ = 2
    const int b  = bp / P_,  p = bp % P_;
    const int tid = threadIdx.x;
    const int row0 = (p / 6) * 2, col0 = (p % 6) * 2;

    // stage pose/act ONCE (reused by all 3 passes)
    for (int f = tid; f < CG * 4; f += THREADS) {
        const int fq = g * (CG * 4) + f;        // float4 index in the 9x128 pixel space
        const int qw = fq >> 7, r = fq & 127;
        const int pix = (row0 + qw / 3) * SIZE_IN + (col0 + qw % 3);
        reinterpret_cast<float4*>(sm.pose)[f] =
            reinterpret_cast<const float4*>(in_pose + (size_t)(b * 196 + pix) * 512)[r];
    }
    for (int idx = tid; idx < CG; idx += THREADS) {
        const int c = g * CG + idx;
        const int qw = c >> 5, ic = c & 31;
        const int pix = (row0 + qw / 3) * SIZE_IN + (col0 + qw % 3);
        sm.act[idx] = in_act[(size_t)(b * 196 + pix) * 32 + ic];
    }
    __syncthreads();

    const int o  = tid & 31;
    const int ci = tid >> 5;

    for (int iter = 0; iter < 3; ++iter) {
        float* Pcur = (iter == 1) ? P2 : P1;
        const float* Pprev = (iter == 1) ? P1 : P2;
        if (iter > 0) {  // finalize previous pass partials into sm.miv (redundant per block, cheap)
            fin_phase<false>(sm, Pprev, beta_a, beta_v,
                             (iter == 1) ? 0.0f : 0.0005f, bp, nullptr);
            __syncthreads();
        }

        float m[16], iv[16], zb = 0.f;
        if (iter > 0) {
            #pragma unroll
            for (int j = 0; j < 16; ++j) { m[j] = sm.miv[o][j]; iv[j] = sm.miv[o][16 + j]; }
            zb = sm.miv[o][32];
        }

        float S0 = 0.f, S1[16], S2[16];
        #pragma unroll
        for (int j = 0; j < 16; ++j) { S1[j] = 0.f; S2[j] = 0.f; }

        const float4* wp0 = reinterpret_cast<const float4*>(W + (size_t)((g * CG + ci) * O_ + o) * 16);
        float4 nw0 = wp0[0], nw1 = wp0[1], nw2 = wp0[2], nw3 = wp0[3];
        const float4* pp0 = reinterpret_cast<const float4*>(&sm.pose[ci * 16]);
        float4 np0 = pp0[0], np1 = pp0[1], np2 = pp0[2], np3 = pp0[3];

        #pragma unroll 1   // do NOT unroll: short-loop full-unroll => register blowup (r10/r11)
        for (int t = 0; t < NTG; ++t) {
            const int cl = t * 8 + ci;
            float w[16], q[16];
            F4_TO_ARR(w, 0, nw0) F4_TO_ARR(w, 4, nw1) F4_TO_ARR(w, 8, nw2) F4_TO_ARR(w, 12, nw3)
            F4_TO_ARR(q, 0, np0) F4_TO_ARR(q, 4, np1) F4_TO_ARR(q, 8, np2) F4_TO_ARR(q, 12, np3)
            if (t + 1 < NTG) {
                const int cn = g * CG + cl + 8;
                const float4* wn = reinterpret_cast<const float4*>(W + (size_t)(cn * O_ + o) * 16);
                nw0 = wn[0]; nw1 = wn[1]; nw2 = wn[2]; nw3 = wn[3];
                const float4* pn = reinterpret_cast<const float4*>(&sm.pose[(cl + 8) * 16]);
                np0 = pn[0]; np1 = pn[1]; np2 = pn[2]; np3 = pn[3];
            }

            float v[16];
            #pragma unroll
            for (int i = 0; i < 4; ++i) {
                #pragma unroll
                for (int jj = 0; jj < 4; ++jj) {
                    float acc = q[i*4+0] * w[0*4+jj];
                    acc = fmaf(q[i*4+1], w[1*4+jj], acc);
                    acc = fmaf(q[i*4+2], w[2*4+jj], acc);
                    acc = fmaf(q[i*4+3], w[3*4+jj], acc);
                    v[i*4+jj] = acc;
                }
            }

            float ws;
            if (iter > 0) {
                float s = 0.f;
                #pragma unroll
                for (int j = 0; j < 16; ++j) { float d = v[j] - m[j]; s = fmaf(d * d, iv[j], s); }
                float zz = zb - s;
                float mx = red32_max(zz);
                float e = __expf(zz - mx);
                float sum = red32_sum(e);
                ws = (e / sum) * sm.act[cl];
            } else {
                ws = sm.act[cl] * (1.0f / 32.0f);   // iteration 0: rr uniform
            }

            S0 += ws;
            #pragma unroll
            for (int j = 0; j < 16; ++j) {
                float t0 = ws * v[j];
                S1[j] += t0;
                S2[j] = fmaf(t0, v[j], S2[j]);
            }
        }

        S0 += __shfl_xor(S0, 32);
        #pragma unroll
        for (int j = 0; j < 16; ++j) {
            S1[j] += __shfl_xor(S1[j], 32);
            S2[j] += __shfl_xor(S2[j], 32);
        }
        if (!(tid & 32)) {
            const int wv = tid >> 6;
            float* r = sm.red[wv][o];
            r[0] = S0;
            #pragma unroll
            for (int j = 0; j < 16; ++j) { r[1 + j] = S1[j]; r[17 + j] = S2[j]; }
        }
        __syncthreads();

        float* slot = Pcur + (size_t)(bp * G_ + g) * O_ * 33;
        for (int idx = tid; idx < O_ * 33; idx += THREADS) {
            const int oo = idx / 33, k = idx - oo * 33;
            slot[idx] = sm.red[0][oo][k] + sm.red[1][oo][k] + sm.red[2][oo][k] + sm.red[3][oo][k];
        }

        gridbar(&bars[iter]);   // all partials of this pass visible grid-wide
    }

    // pass 2 wrote P1; one block per bp emits the outputs
    if (g == 0)
        fin_phase<true>(sm, P1, beta_a, beta_v, 0.000975f, bp, out);
}

// ===================== PATH B: fused single kernel (round 8, proven, 91 us) =====================
struct __align__(16) SMem {
    float pose[Cc * 16];
    float act[Cc];
    float red[4][O_][33];
    float mean[O_][17];
    float iv[O_][17];
    float zb[O_];
};

template<bool HASE, bool LAST>
__device__ __forceinline__ void em_pass(
    SMem& sm, const float* __restrict__ W,
    const float* __restrict__ beta_a, const float* __restrict__ beta_v,
    float lambda, int bp, float* __restrict__ out)
{
    const int tid = threadIdx.x;
    const int o  = tid & 31;
    const int ci = tid >> 5;

    float m[16], iv[16], zb = 0.f;
    if (HASE) {
        #pragma unroll
        for (int j = 0; j < 16; ++j) { m[j] = sm.mean[o][j]; iv[j] = sm.iv[o][j]; }
        zb = sm.zb[o];
    }

    float S0 = 0.f, S1[16], S2[16];
    #pragma unroll
    for (int j = 0; j < 16; ++j) { S1[j] = 0.f; S2[j] = 0.f; }

    const float4* wp0 = reinterpret_cast<const float4*>(W + (size_t)(ci * O_ + o) * 16);
    float4 nw0 = wp0[0], nw1 = wp0[1], nw2 = wp0[2], nw3 = wp0[3];
    const float4* pp0 = reinterpret_cast<const float4*>(&sm.pose[ci * 16]);
    float4 np0 = pp0[0], np1 = pp0[1], np2 = pp0[2], np3 = pp0[3];

    #pragma unroll 2
    for (int t = 0; t < 36; ++t) {
        const int c = t * 8 + ci;
        float w[16], q[16];
        F4_TO_ARR(w, 0, nw0) F4_TO_ARR(w, 4, nw1) F4_TO_ARR(w, 8, nw2) F4_TO_ARR(w, 12, nw3)
        F4_TO_ARR(q, 0, np0) F4_TO_ARR(q, 4, np1) F4_TO_ARR(q, 8, np2) F4_TO_ARR(q, 12, np3)
        if (t + 1 < 36) {
            const int cn = c + 8;
            const float4* wn = reinterpret_cast<const float4*>(W + (size_t)(cn * O_ + o) * 16);
            nw0 = wn[0]; nw1 = wn[1]; nw2 = wn[2]; nw3 = wn[3];
            const float4* pn = reinterpret_cast<const float4*>(&sm.pose[cn * 16]);
            np0 = pn[0]; np1 = pn[1]; np2 = pn[2]; np3 = pn[3];
        }

        float v[16];
        #pragma unroll
        for (int i = 0; i < 4; ++i) {
            #pragma unroll
            for (int jj = 0; jj < 4; ++jj) {
                float acc = q[i*4+0] * w[0*4+jj];
                acc = fmaf(q[i*4+1], w[1*4+jj], acc);
                acc = fmaf(q[i*4+2], w[2*4+jj], acc);
                acc = fmaf(q[i*4+3], w[3*4+jj], acc);
                v[i*4+jj] = acc;
            }
        }

        float ws;
        if (HASE) {
            float s = 0.f;
            #pragma unroll
            for (int j = 0; j < 16; ++j) { float d = v[j] - m[j]; s = fmaf(d * d, iv[j], s); }
            float zz = zb - s;
            float mx = red32_max(zz);
            float e = __expf(zz - mx);
            float sum = red32_sum(e);
            ws = (e / sum) * sm.act[c];
        } else {
            ws = sm.act[c] * (1.0f / 32.0f);
        }

        S0 += ws;
        #pragma unroll
        for (int j = 0; j < 16; ++j) {
            float t0 = ws * v[j];
            S1[j] += t0;
            S2[j] = fmaf(t0, v[j], S2[j]);
        }
    }

    S0 += __shfl_xor(S0, 32);
    #pragma unroll
    for (int j = 0; j < 16; ++j) {
        S1[j] += __shfl_xor(S1[j], 32);
        S2[j] += __shfl_xor(S2[j], 32);
    }
    if (!(tid & 32)) {
        const int wv = tid >> 6;
        float* r = sm.red[wv][o];
        r[0] = S0;
        #pragma unroll
        for (int j = 0; j < 16; ++j) { r[1 + j] = S1[j]; r[17 + j] = S2[j]; }
    }
    __syncthreads();

    #pragma unroll
    for (int half = 0; half < 2; ++half) {
        const int of = (tid >> 4) + half * 16, jf = tid & 15;
        const float* r0 = sm.red[0][of];
        const float* r1 = sm.red[1][of];
        const float* r2 = sm.red[2][of];
        const float* r3 = sm.red[3][of];
        float s0 = r0[0] + r1[0] + r2[0] + r3[0];
        float s1 = r0[1+jf] + r1[1+jf] + r2[1+jf] + r3[1+jf];
        float s2 = r0[17+jf] + r1[17+jf] + r2[17+jf] + r3[17+jf];
        float denom = s0 + EPS;
        float mj = s1 / denom;
        float varn = fmaxf(s2 - 2.f * mj * s1 + mj * mj * s0, 0.f);
        float sd = sqrtf(varn / denom);
        float sumlog = red16_sum(__logf(sd + EPS));
        if (!LAST) {
            sm.mean[of][jf] = mj;
            sm.iv[of][jf] = 1.f / fmaf(2.f * sd, sd, EPS);
            if (jf == 0) {
                float cost = fmaf(16.f, beta_v[of], s0 * sumlog);
                float oact = 1.f / (1.f + __expf(-(lambda * (beta_a[of] - cost))));
                sm.zb[of] = __logf(oact + EPS) - sumlog;
            }
        } else {
            out[NBP * O_ + ((size_t)bp * O_ + of) * 16 + jf] = mj;
            if (jf == 0) {
                float cost = fmaf(16.f, beta_v[of], s0 * sumlog);
                float oact = 1.f / (1.f + __expf(-(lambda * (beta_a[of] - cost))));
                out[bp * O_ + of] = oact;
            }
        }
    }
    __syncthreads();
}

__global__ __launch_bounds__(THREADS, 2) void convcaps_fused(
    const float* __restrict__ in_act, const float* __restrict__ in_pose,
    const float* __restrict__ W, const float* __restrict__ beta_a,
    const float* __restrict__ beta_v, float* __restrict__ out)
{
    __shared__ SMem sm;
    const int bp = blockIdx.x;
    const int b  = bp / P_;
    const int p  = bp % P_;
    const int tid = threadIdx.x;
    const int row0 = (p / 6) * 2, col0 = (p % 6) * 2;

    for (int f = tid; f < 9 * 128; f += THREADS) {
        const int qw = f >> 7, r = f & 127;
        const int pix = (row0 + qw / 3) * SIZE_IN + (col0 + qw % 3);
        reinterpret_cast<float4*>(sm.pose)[qw * 128 + r] =
            reinterpret_cast<const float4*>(in_pose + (size_t)(b * 196 + pix) * 512)[r];
    }
    for (int idx = tid; idx < Cc; idx += THREADS) {
        const int qw = idx >> 5, ic = idx & 31;
        const int pix = (row0 + qw / 3) * SIZE_IN + (col0 + qw % 3);
        sm.act[idx] = in_act[(size_t)(b * 196 + pix) * 32 + ic];
    }
    __syncthreads();

    em_pass<false, false>(sm, W, beta_a, beta_v, 0.0f,      bp, out);
    em_pass<true,  false>(sm, W, beta_a, beta_v, 0.0005f,   bp, out);
    em_pass<true,  true >(sm, W, beta_a, beta_v, 0.000975f, bp, out);
}

// ============================ dispatch ============================
// Persistent path requires ALL 576 blocks co-resident (software grid barrier).
// Residency is VERIFIED via the occupancy calculator; otherwise fall back to
// the proven fused kernel. Both branches are launch-constant -> graph-safe.
extern "C" void kernel_launch(void* const* d_in, const int* in_sizes, int n_in,
                              void* d_out, int out_size, void* d_ws, size_t ws_size,
                              hipStream_t stream) {
    const float* in_act  = (const float*)d_in[0];
    const float* in_pose = (const float*)d_in[1];
    const float* W       = (const float*)d_in[2];
    const float* beta_a  = (const float*)d_in[3];
    const float* beta_v  = (const float*)d_in[4];
    float* out = (float*)d_out;

    const size_t p_elems = (size_t)NBP * G_ * O_ * 33;     // 608,256 floats (2.43 MB)
    const size_t need = 2 * p_elems * sizeof(float) + 64;  // P1 + P2 + barrier counters

    int maxblk_per_cu = 0;
    (void)hipOccupancyMaxActiveBlocksPerMultiprocessor(&maxblk_per_cu, caps_all, THREADS, 0);
    const bool resident_ok = (maxblk_per_cu * 256 >= NBLK);   // MI355X: 256 CUs

    if (ws_size >= need && resident_ok) {
        float* P1 = (float*)d_ws;
        float* P2 = P1 + p_elems;
        unsigned* bars = (unsigned*)(P2 + p_elems);
        hipMemsetAsync(bars, 0, 3 * sizeof(unsigned), stream);
        caps_all<<<dim3(NBLK), dim3(THREADS), 0, stream>>>(
            in_act, in_pose, W, beta_a, beta_v, out, P1, P2, bars);
    } else {
        convcaps_fused<<<dim3(NBP), dim3(THREADS), 0, stream>>>(
            in_act, in_pose, W, beta_a, beta_v, out);
    }
}